// Round 5
// baseline (107.820 us; speedup 1.0000x reference)
//
#include <hip/hip_runtime.h>
#include <hip/hip_bf16.h>

#define NUM_SEGMENTS 50000

typedef float f32x4 __attribute__((ext_vector_type(4)));

__device__ __forceinline__ f32x4 ntload4(const f32x4* p) {
    return __builtin_nontemporal_load(p);
}
__device__ __forceinline__ void ntstore4(f32x4* p, f32x4 v) {
    __builtin_nontemporal_store(v, p);
}

// lower_bound over [lo, hi)
__device__ __forceinline__ int lb_range(const int* __restrict__ idx,
                                        int lo, int hi, int s) {
    while (lo < hi) {
        int mid = (lo + hi) >> 1;
        if (idx[mid] < s) lo = mid + 1; else hi = mid;
    }
    return lo;
}

// lower_bound(idx, s) with a windowed search around the expected position
// (index ~ uniform => boundary near s*n/S; +-6144 = ~12 sigma). The verify-
// and-fallback paths make the result correct for ANY sorted distribution.
__device__ __forceinline__ int lb_guess(const int* __restrict__ idx,
                                        int n, int S, int s) {
    if (s <= 0) return 0;
    if (s >= S) return n;
    long long g = (long long)s * n / S;
    int lo = (int)g - 6144; if (lo < 0) lo = 0;
    int hi = (int)g + 6144; if (hi > n) hi = n;
    int r = lb_range(idx, lo, hi, s);
    if (r == lo && lo > 0 && idx[r - 1] >= s)      r = lb_range(idx, 0, lo, s);
    else if (r == hi && hi < n && idx[r] < s)      r = lb_range(idx, hi, n, s);
    return r;
}

// Accumulate one segment's rows for this thread (col4, row-group rg).
__device__ __forceinline__ void accum_seg(const f32x4* __restrict__ prop4,
                                          const float* __restrict__ w,
                                          int start, int nrows,
                                          int col4, int rg,
                                          f32x4& acc, float& wsum) {
    const f32x4* p  = prop4 + (size_t)(start + rg) * 32 + col4;
    const float* wp = w + start;
    int r = rg;
    for (; r + 4 < nrows; r += 8) {
        float w0 = wp[r], w1 = wp[r + 4];
        f32x4 p0 = ntload4(p), p1 = ntload4(p + 128);
        p += 256;
        acc += p0 * w0;
        acc += p1 * w1;
        wsum += w0 + w1;
    }
    for (; r < nrows; r += 4) {
        float w0 = wp[r];
        f32x4 p0 = ntload4(p);
        p += 128;
        acc += p0 * w0;
        wsum += w0;
    }
}

// Specialized d=128. One block (128 thr) per TWO consecutive segments.
// Segment bounds found in-kernel by windowed binary search (lanes 0..2,
// lockstep-parallel) -- no prepass kernel, single launch.
__global__ void __launch_bounds__(128)
seg_weighted_avg_d128(const f32x4* __restrict__ prop4,
                      const float* __restrict__ w,
                      const int*   __restrict__ idx,
                      f32x4*       __restrict__ out4,
                      int n, int S) {
    const int s0 = blockIdx.x * 2;
    const int t  = threadIdx.x;

    __shared__ int sb[3];
    if (t < 3) sb[t] = lb_guess(idx, n, S, s0 + t);
    __syncthreads();
    const int st0 = sb[0], st1 = sb[1], st2 = sb[2];

    const int col4 = t & 31;
    const int rg   = t >> 5;

    f32x4 accA = (f32x4)0.f, accB = (f32x4)0.f;
    float wsA = 0.f, wsB = 0.f;

    accum_seg(prop4, w, st0, st1 - st0, col4, rg, accA, wsA);
    accum_seg(prop4, w, st1, st2 - st1, col4, rg, accB, wsB);

    __shared__ f32x4 laccA[128], laccB[128];
    __shared__ float lwA[128], lwB[128];
    laccA[t] = accA; laccB[t] = accB;
    lwA[t]   = wsA;  lwB[t]   = wsB;
    __syncthreads();

    if (t < 64) {
        const f32x4* lacc = (t < 32) ? laccA : laccB;
        const float* lw   = (t < 32) ? lwA   : lwB;
        const int u = t & 31;
        f32x4 a = (lacc[u] + lacc[u + 32]) + (lacc[u + 64] + lacc[u + 96]);
        float ws = (lw[u] + lw[u + 32]) + (lw[u + 64] + lw[u + 96]);
        // 0/0 -> NaN for empty segments, matching the JAX reference.
        ntstore4((f32x4*)&out4[(size_t)(s0 + (t >> 5)) * 32 + u], a / ws);
    }
}

// Generic fallback (d != 128): per-segment block, in-kernel binary search.
__global__ void __launch_bounds__(128)
seg_weighted_avg_generic(const float* __restrict__ prop,
                         const float* __restrict__ w,
                         const int*   __restrict__ idx,
                         float*       __restrict__ out,
                         int n, int S, int d) {
    const int s = blockIdx.x;
    const int t = threadIdx.x;
    __shared__ int sb[2];
    if (t < 2) sb[t] = lb_guess(idx, n, S, s + t);
    __syncthreads();
    const int start = sb[0], end = sb[1];
    const float* p  = prop + (size_t)start * d + t;
    float acc = 0.f, wsum = 0.f;
    for (int i = start; i < end; ++i) {
        float wi = w[i];
        wsum += wi;
        acc = fmaf(wi, p[0], acc);
        p += d;
    }
    out[(size_t)s * d + t] = acc / wsum;
}

extern "C" void kernel_launch(void* const* d_in, const int* in_sizes, int n_in,
                              void* d_out, int out_size, void* d_ws, size_t ws_size,
                              hipStream_t stream) {
    const float* prop = (const float*)d_in[0];
    const float* w    = (const float*)d_in[1];
    const int*   idx  = (const int*)d_in[2];
    float* out        = (float*)d_out;

    const int n = in_sizes[1];                // 1,000,000
    const int d = in_sizes[0] / in_sizes[1];  // 128
    const int S = NUM_SEGMENTS;

    if (d == 128 && (S % 2) == 0) {
        seg_weighted_avg_d128<<<S / 2, 128, 0, stream>>>(
            (const f32x4*)prop, w, idx, (f32x4*)out, n, S);
    } else {
        seg_weighted_avg_generic<<<S, d, 0, stream>>>(prop, w, idx, out, n, S, d);
    }
}

// Round 6
// 99.858 us; speedup vs baseline: 1.0797x; 1.0797x over previous
//
#include <hip/hip_runtime.h>
#include <hip/hip_bf16.h>

#define NUM_SEGMENTS 50000

typedef float f32x4 __attribute__((ext_vector_type(4)));

__device__ __forceinline__ f32x4 ntload4(const f32x4* p) {
    return __builtin_nontemporal_load(p);
}
__device__ __forceinline__ void ntstore4(f32x4* p, f32x4 v) {
    __builtin_nontemporal_store(v, p);
}

// Prepass: starts[s] = lower_bound(idx, s); starts[S] = n.
// int4-vectorized; neighbor value comes from __shfl_up (only lane 0 of each
// wave re-loads idx[base-1]). Every starts[] entry written exactly once.
__global__ void build_starts_v4(const int4* __restrict__ idx4,
                                const int*  __restrict__ idx,
                                int* __restrict__ starts,
                                int n4, int n, int S) {
    int i4 = blockIdx.x * blockDim.x + threadIdx.x;
    if (i4 >= n4) return;
    int4 v = idx4[i4];
    int base = i4 * 4;
    int lane = threadIdx.x & 63;
    int prevw = __shfl_up(v.w, 1);
    int prev = (lane == 0) ? ((base == 0) ? -1 : idx[base - 1]) : prevw;
    int a0 = v.x, a1 = v.y, a2 = v.z, a3 = v.w;
    for (int s = prev + 1; s <= a0; ++s) starts[s] = base;
    for (int s = a0 + 1;  s <= a1; ++s) starts[s] = base + 1;
    for (int s = a1 + 1;  s <= a2; ++s) starts[s] = base + 2;
    for (int s = a2 + 1;  s <= a3; ++s) starts[s] = base + 3;
    if (base + 4 >= n) {
        for (int s = a3 + 1; s <= S; ++s) starts[s] = n;
    }
}

// Tail for n not divisible by 4 (no-op for the expected n=1M).
__global__ void build_starts_tail(const int* __restrict__ idx,
                                  int* __restrict__ starts,
                                  int n4, int n, int S) {
    int i = n4 * 4 + blockIdx.x * blockDim.x + threadIdx.x;
    if (i >= n) return;
    int cur = idx[i];
    int prev = (i == 0) ? -1 : idx[i - 1];
    for (int s = prev + 1; s <= cur; ++s) starts[s] = i;
    if (i == n - 1)
        for (int s = cur + 1; s <= S; ++s) starts[s] = n;
}

// Accumulate one segment's rows for this thread (col4 = t&31, row-group rg).
__device__ __forceinline__ void accum_seg(const f32x4* __restrict__ prop4,
                                          const float* __restrict__ w,
                                          int start, int nrows,
                                          int col4, int rg,
                                          f32x4& acc, float& wsum) {
    const f32x4* p  = prop4 + (size_t)(start + rg) * 32 + col4;
    const float* wp = w + start;
    int r = rg;
    for (; r + 4 < nrows; r += 8) {
        float w0 = wp[r], w1 = wp[r + 4];
        f32x4 p0 = ntload4(p), p1 = ntload4(p + 128);
        p += 256;
        acc += p0 * w0;
        acc += p1 * w1;
        wsum += w0 + w1;
    }
    for (; r < nrows; r += 4) {
        float w0 = wp[r];
        f32x4 p0 = ntload4(p);
        p += 128;
        acc += p0 * w0;
        wsum += w0;
    }
}

// Specialized d=128. One block (128 thr) per FOUR consecutive segments.
// Bounds are wave-uniform scalar loads from the prepass's starts[].
// Epilogue: LDS-reduce the 4 row-groups; 128 threads store 2KB contiguous.
__global__ void __launch_bounds__(128)
seg_weighted_avg_d128(const f32x4* __restrict__ prop4,
                      const float* __restrict__ w,
                      const int*   __restrict__ starts,
                      f32x4*       __restrict__ out4) {
    const int s0 = blockIdx.x * 4;
    const int t  = threadIdx.x;

    const int b0 = starts[s0],     b1 = starts[s0 + 1];
    const int b2 = starts[s0 + 2], b3 = starts[s0 + 3];
    const int b4 = starts[s0 + 4];

    const int col4 = t & 31;
    const int rg   = t >> 5;

    f32x4 accA = (f32x4)0.f, accB = (f32x4)0.f;
    f32x4 accC = (f32x4)0.f, accD = (f32x4)0.f;
    float wsA = 0.f, wsB = 0.f, wsC = 0.f, wsD = 0.f;

    accum_seg(prop4, w, b0, b1 - b0, col4, rg, accA, wsA);
    accum_seg(prop4, w, b1, b2 - b1, col4, rg, accB, wsB);
    accum_seg(prop4, w, b2, b3 - b2, col4, rg, accC, wsC);
    accum_seg(prop4, w, b3, b4 - b3, col4, rg, accD, wsD);

    __shared__ f32x4 lacc[4][128];
    __shared__ float lws[4][4];
    lacc[0][t] = accA; lacc[1][t] = accB;
    lacc[2][t] = accC; lacc[3][t] = accD;
    if ((t & 31) == 0) {            // lanes in a row-group hold identical wsum
        lws[0][rg] = wsA; lws[1][rg] = wsB;
        lws[2][rg] = wsC; lws[3][rg] = wsD;
    }
    __syncthreads();

    const int seg = t >> 5, u = t & 31;
    f32x4 a = (lacc[seg][u] + lacc[seg][u + 32]) +
              (lacc[seg][u + 64] + lacc[seg][u + 96]);
    float ws = (lws[seg][0] + lws[seg][1]) + (lws[seg][2] + lws[seg][3]);
    // 0/0 -> NaN for empty segments, matching the JAX reference.
    ntstore4(&out4[(size_t)(s0 + seg) * 32 + u], a / ws);
}

// Generic fallback (d != 128 or S % 4 != 0).
__global__ void __launch_bounds__(128)
seg_weighted_avg_generic(const float* __restrict__ prop,
                         const float* __restrict__ w,
                         const int*   __restrict__ starts,
                         float*       __restrict__ out,
                         int d) {
    const int s     = blockIdx.x;
    const int start = starts[s];
    const int end   = starts[s + 1];
    const int t     = threadIdx.x;
    const float* p  = prop + (size_t)start * d + t;
    float acc = 0.f, wsum = 0.f;
    for (int i = start; i < end; ++i) {
        float wi = w[i];
        wsum += wi;
        acc = fmaf(wi, p[0], acc);
        p += d;
    }
    out[(size_t)s * d + t] = acc / wsum;
}

extern "C" void kernel_launch(void* const* d_in, const int* in_sizes, int n_in,
                              void* d_out, int out_size, void* d_ws, size_t ws_size,
                              hipStream_t stream) {
    const float* prop = (const float*)d_in[0];
    const float* w    = (const float*)d_in[1];
    const int*   idx  = (const int*)d_in[2];
    float* out        = (float*)d_out;

    const int n = in_sizes[1];                // 1,000,000
    const int d = in_sizes[0] / in_sizes[1];  // 128
    const int S = NUM_SEGMENTS;

    int* starts = (int*)d_ws;                 // (S+1) ints << ws_size

    const int n4 = n / 4;
    build_starts_v4<<<(n4 + 255) / 256, 256, 0, stream>>>(
        (const int4*)idx, idx, starts, n4, n, S);
    if (n % 4) {
        build_starts_tail<<<((n - n4 * 4) + 255) / 256, 256, 0, stream>>>(
            idx, starts, n4, n, S);
    }

    if (d == 128 && (S % 4) == 0) {
        seg_weighted_avg_d128<<<S / 4, 128, 0, stream>>>(
            (const f32x4*)prop, w, starts, (f32x4*)out);
    } else {
        seg_weighted_avg_generic<<<S, d, 0, stream>>>(prop, w, starts, out, d);
    }
}

// Round 7
// 96.785 us; speedup vs baseline: 1.1140x; 1.0318x over previous
//
#include <hip/hip_runtime.h>
#include <hip/hip_bf16.h>

#define NUM_SEGMENTS 50000

typedef float f32x4 __attribute__((ext_vector_type(4)));

__device__ __forceinline__ f32x4 ntload4(const f32x4* p) {
    return __builtin_nontemporal_load(p);
}
__device__ __forceinline__ void ntstore4(f32x4* p, f32x4 v) {
    __builtin_nontemporal_store(v, p);
}

// Prepass: starts[s] = lower_bound(idx, s); starts[S] = n.
// int4-vectorized; neighbor value via __shfl_up (only lane 0 of each wave
// re-loads idx[base-1]). Every starts[] entry written exactly once per call.
__global__ void build_starts_v4(const int4* __restrict__ idx4,
                                const int*  __restrict__ idx,
                                int* __restrict__ starts,
                                int n4, int n, int S) {
    int i4 = blockIdx.x * blockDim.x + threadIdx.x;
    if (i4 >= n4) return;
    int4 v = idx4[i4];
    int base = i4 * 4;
    int lane = threadIdx.x & 63;
    int prevw = __shfl_up(v.w, 1);
    int prev = (lane == 0) ? ((base == 0) ? -1 : idx[base - 1]) : prevw;
    int a0 = v.x, a1 = v.y, a2 = v.z, a3 = v.w;
    for (int s = prev + 1; s <= a0; ++s) starts[s] = base;
    for (int s = a0 + 1;  s <= a1; ++s) starts[s] = base + 1;
    for (int s = a1 + 1;  s <= a2; ++s) starts[s] = base + 2;
    for (int s = a2 + 1;  s <= a3; ++s) starts[s] = base + 3;
    if (base + 4 >= n) {
        for (int s = a3 + 1; s <= S; ++s) starts[s] = n;
    }
}

// Tail for n not divisible by 4 (no-op for the expected n=1M).
__global__ void build_starts_tail(const int* __restrict__ idx,
                                  int* __restrict__ starts,
                                  int n4, int n, int S) {
    int i = n4 * 4 + blockIdx.x * blockDim.x + threadIdx.x;
    if (i >= n) return;
    int cur = idx[i];
    int prev = (i == 0) ? -1 : idx[i - 1];
    for (int s = prev + 1; s <= cur; ++s) starts[s] = i;
    if (i == n - 1)
        for (int s = cur + 1; s <= S; ++s) starts[s] = n;
}

// Accumulate one segment's rows for this thread (col4 = t&31, row-group rg).
__device__ __forceinline__ void accum_seg(const f32x4* __restrict__ prop4,
                                          const float* __restrict__ w,
                                          int start, int nrows,
                                          int col4, int rg,
                                          f32x4& acc, float& wsum) {
    const f32x4* p  = prop4 + (size_t)(start + rg) * 32 + col4;
    const float* wp = w + start;
    int r = rg;
    for (; r + 4 < nrows; r += 8) {
        float w0 = wp[r], w1 = wp[r + 4];
        f32x4 p0 = ntload4(p), p1 = ntload4(p + 128);
        p += 256;
        acc += p0 * w0;
        acc += p1 * w1;
        wsum += w0 + w1;
    }
    for (; r < nrows; r += 4) {
        float w0 = wp[r];
        f32x4 p0 = ntload4(p);
        p += 128;
        acc += p0 * w0;
        wsum += w0;
    }
}

// Specialized d=128. One block (128 thr) per TWO consecutive segments.
// Thread t: float4-column (t&31), row-group (t>>5).
__global__ void __launch_bounds__(128)
seg_weighted_avg_d128(const f32x4* __restrict__ prop4,
                      const float* __restrict__ w,
                      const int*   __restrict__ starts,
                      f32x4*       __restrict__ out4) {
    const int s0  = blockIdx.x * 2;
    const int st0 = starts[s0];
    const int st1 = starts[s0 + 1];
    const int st2 = starts[s0 + 2];

    const int t    = threadIdx.x;
    const int col4 = t & 31;
    const int rg   = t >> 5;

    f32x4 accA = (f32x4)0.f, accB = (f32x4)0.f;
    float wsA = 0.f, wsB = 0.f;

    accum_seg(prop4, w, st0, st1 - st0, col4, rg, accA, wsA);
    accum_seg(prop4, w, st1, st2 - st1, col4, rg, accB, wsB);

    __shared__ f32x4 laccA[128], laccB[128];
    __shared__ float lwA[128], lwB[128];
    laccA[t] = accA; laccB[t] = accB;
    lwA[t]   = wsA;  lwB[t]   = wsB;
    __syncthreads();

    if (t < 64) {
        const f32x4* lacc = (t < 32) ? laccA : laccB;
        const float* lw   = (t < 32) ? lwA   : lwB;
        const int u = t & 31;
        f32x4 a = (lacc[u] + lacc[u + 32]) + (lacc[u + 64] + lacc[u + 96]);
        float ws = (lw[u] + lw[u + 32]) + (lw[u + 64] + lw[u + 96]);
        // 0/0 -> NaN for empty segments, matching the JAX reference.
        ntstore4((f32x4*)&out4[(size_t)(s0 + (t >> 5)) * 32 + u], a / ws);
    }
}

// Generic fallback (d != 128 or S odd).
__global__ void __launch_bounds__(128)
seg_weighted_avg_generic(const float* __restrict__ prop,
                         const float* __restrict__ w,
                         const int*   __restrict__ starts,
                         float*       __restrict__ out,
                         int d) {
    const int s     = blockIdx.x;
    const int start = starts[s];
    const int end   = starts[s + 1];
    const int t     = threadIdx.x;
    const float* p  = prop + (size_t)start * d + t;
    float acc = 0.f, wsum = 0.f;
    for (int i = start; i < end; ++i) {
        float wi = w[i];
        wsum += wi;
        acc = fmaf(wi, p[0], acc);
        p += d;
    }
    out[(size_t)s * d + t] = acc / wsum;
}

extern "C" void kernel_launch(void* const* d_in, const int* in_sizes, int n_in,
                              void* d_out, int out_size, void* d_ws, size_t ws_size,
                              hipStream_t stream) {
    const float* prop = (const float*)d_in[0];
    const float* w    = (const float*)d_in[1];
    const int*   idx  = (const int*)d_in[2];
    float* out        = (float*)d_out;

    const int n = in_sizes[1];                // 1,000,000
    const int d = in_sizes[0] / in_sizes[1];  // 128
    const int S = NUM_SEGMENTS;

    int* starts = (int*)d_ws;                 // (S+1) ints << ws_size

    const int n4 = n / 4;
    build_starts_v4<<<(n4 + 255) / 256, 256, 0, stream>>>(
        (const int4*)idx, idx, starts, n4, n, S);
    if (n % 4) {
        build_starts_tail<<<((n - n4 * 4) + 255) / 256, 256, 0, stream>>>(
            idx, starts, n4, n, S);
    }

    if (d == 128 && (S % 2) == 0) {
        seg_weighted_avg_d128<<<S / 2, 128, 0, stream>>>(
            (const f32x4*)prop, w, starts, (f32x4*)out);
    } else {
        seg_weighted_avg_generic<<<S, d, 0, stream>>>(prop, w, starts, out, d);
    }
}